// Round 8
// baseline (13891.719 us; speedup 1.0000x reference)
//
#include <hip/hip_runtime.h>

// liGRU on MI355X.
// Phase 1: P[64000][2048](bf16, in d_out) = x @ [Wh;Wz]^T + column sums/sumsq.
// Phase 2: persistent scan, 8 groups (4 batch rows) x 32 WGs x 4 waves, BARRIER-FREE
//          chunk-streamed exchange:
//          - records reindexed by chunk c=role (32 units = one kt slice):
//            hrec[g][par][c*64 + row*16 + pair] = u64{ tag=t+1 | 2x bf16 }.
//            Staging: ONE 8B system-scope load per lane per chunk (512B coalesced),
//            __all on 64 embedded tags, per-chunk retry. Flag IS the data (r2-proven).
//          - wave w stages chunks c==w (mod 4) into LDS + release-stores an LDS flag;
//            all waves consume chunks 0..31 via acquire-spin on LDS flags (no s_barrier
//            in the whole loop). A straggler chunk delays only its own ~40cy slot.
//          - hlds[par] WAR across same-parity steps guarded by LDS counter lcnt[par]
//            (all 4 waves release-add after consuming; stager acquire-spins >= 4*(t>>1)).
//          - no sc0/sc1 hand asm (r4 hang), no tag indirection (r6 regression),
//            no >128-VGPR fragment sets (r3 spill).
//          WAR on d_out aliasing (P bf16 read vs out f32 write): P[t+2] loads issued at
//          step t are drained by step t's staging waitcnt; thus P[t+1] (issued t-1)
//          completed before any tag-(t+1) record store (epilogue t); a writer of
//          out[t+1] consumed all 32 chunks with tag>=t+1 first. Prologue rendezvous
//          covers P[0..1].

#define T_STEPS 2000
#define NCOLS   2048
#define PKEEP   0.8f
#define BN_EPSF 1e-5f
#define NWG     256

typedef __attribute__((ext_vector_type(8))) short bf16x8;
typedef __attribute__((ext_vector_type(4))) float f32x4;
typedef __attribute__((ext_vector_type(4))) unsigned int u32x4;

static __device__ __forceinline__ unsigned short f2bf(float f) {
  unsigned u = __builtin_bit_cast(unsigned, f);
  unsigned r = u + 0x7FFFu + ((u >> 16) & 1u);   // RNE
  return (unsigned short)(r >> 16);
}
static __device__ __forceinline__ float bf2f(unsigned short s) {
  unsigned u = ((unsigned)s) << 16;
  return __builtin_bit_cast(float, u);
}

// ---------------- K1: convert [Wh;Wz] f32 -> bf16 ----------------
__global__ void k_convw(const float* __restrict__ Wh, const float* __restrict__ Wz,
                        unsigned short* __restrict__ Wb) {
  int i = blockIdx.x * 256 + threadIdx.x;
  int e = i * 4;
  int n = e >> 9;
  int k = e & 511;
  const float* src = (n < 1024) ? (Wh + (size_t)n * 512 + k)
                                : (Wz + (size_t)(n - 1024) * 512 + k);
  float4 v = *(const float4*)src;
  *(ushort4*)(Wb + e) = make_ushort4(f2bf(v.x), f2bf(v.y), f2bf(v.z), f2bf(v.w));
}

// ---------------- K2: GEMM  P = x @ Wb^T  (+ BN stats) ----------------
__global__ __launch_bounds__(256, 2) void k_gemm(
    const float* __restrict__ X, const unsigned short* __restrict__ Wb,
    unsigned short* __restrict__ P, float* __restrict__ sums, float* __restrict__ sumsq) {
  __shared__ __align__(16) unsigned short As[128 * 32];
  __shared__ __align__(16) unsigned short Bs[128 * 32];
  const int tid  = threadIdx.x;
  const int bm   = blockIdx.x >> 4, bn = blockIdx.x & 15;
  const int lane = tid & 63, wid = tid >> 6;
  const int wm   = wid >> 1, wn = wid & 1;
  const int lrow = lane & 15, lk = lane >> 4;

  f32x4 acc[4][4] = {};

  for (int kk = 0; kk < 512; kk += 32) {
    __syncthreads();
#pragma unroll
    for (int j = 0; j < 2; ++j) {
      int c = j * 256 + wid * 64 + lane;
      int brow = c >> 2, b8 = (c & 3) * 8;
      const unsigned short* gp = Wb + (size_t)(bn * 128 + brow) * 512 + kk + b8;
      __builtin_amdgcn_global_load_lds(
          (const __attribute__((address_space(1))) unsigned int*)gp,
          (__attribute__((address_space(3))) unsigned int*)(Bs + (size_t)(j * 256 + wid * 64) * 8),
          16, 0, 0);
    }
    {
      int arow = tid >> 1, ahalf = tid & 1;
      const float4* xp = (const float4*)(X + (size_t)(bm * 128 + arow) * 512 + kk + ahalf * 16);
      unsigned v[8];
#pragma unroll
      for (int j = 0; j < 4; ++j) {
        float4 f = xp[j];
        v[j * 2 + 0] = (unsigned)f2bf(f.x) | ((unsigned)f2bf(f.y) << 16);
        v[j * 2 + 1] = (unsigned)f2bf(f.z) | ((unsigned)f2bf(f.w) << 16);
      }
      u32x4* ap = (u32x4*)(As + arow * 32 + ahalf * 16);
      u32x4 t0 = {v[0], v[1], v[2], v[3]};
      u32x4 t1 = {v[4], v[5], v[6], v[7]};
      ap[0] = t0; ap[1] = t1;
    }
    __syncthreads();

    bf16x8 af[4], bfr[4];
#pragma unroll
    for (int mt = 0; mt < 4; ++mt)
      af[mt] = *(const bf16x8*)(As + (wm * 64 + mt * 16 + lrow) * 32 + lk * 8);
#pragma unroll
    for (int nt = 0; nt < 4; ++nt)
      bfr[nt] = *(const bf16x8*)(Bs + (wn * 64 + nt * 16 + lrow) * 32 + lk * 8);
#pragma unroll
    for (int mt = 0; mt < 4; ++mt)
#pragma unroll
      for (int nt = 0; nt < 4; ++nt)
        acc[mt][nt] = __builtin_amdgcn_mfma_f32_16x16x32_bf16(af[mt], bfr[nt], acc[mt][nt], 0, 0, 0);
  }

#pragma unroll
  for (int mt = 0; mt < 4; ++mt)
#pragma unroll
    for (int nt = 0; nt < 4; ++nt) {
      f32x4 a = acc[mt][nt];
      int gcol  = bn * 128 + wn * 64 + nt * 16 + lrow;
      int grow0 = bm * 128 + wm * 64 + mt * 16 + lk * 4;
#pragma unroll
      for (int rr = 0; rr < 4; ++rr)
        P[(size_t)(grow0 + rr) * NCOLS + gcol] = f2bf(a[rr]);
    }
#pragma unroll
  for (int nt = 0; nt < 4; ++nt) {
    float s = 0.f, q = 0.f;
#pragma unroll
    for (int mt = 0; mt < 4; ++mt) {
      f32x4 a = acc[mt][nt];
#pragma unroll
      for (int rr = 0; rr < 4; ++rr) { s += a[rr]; q += a[rr] * a[rr]; }
    }
    s += __shfl_xor(s, 16); s += __shfl_xor(s, 32);
    q += __shfl_xor(q, 16); q += __shfl_xor(q, 32);
    if (lane < 16) {
      int gcol = bn * 128 + wn * 64 + nt * 16 + lrow;
      atomicAdd(&sums[gcol], s);
      atomicAdd(&sumsq[gcol], q);
    }
  }
}

// ---------------- K3: persistent scan (chunk-streamed, barrier-free) ----------------
__global__ __launch_bounds__(256, 1) void k_scan(
    const float* __restrict__ Uh, const float* __restrict__ Uz,
    const float* __restrict__ gwh, const float* __restrict__ bwh,
    const float* __restrict__ gwz, const float* __restrict__ bwz,
    const unsigned short* P,            // aliases d_out (bf16 view) -- no restrict!
    const float* __restrict__ sums, const float* __restrict__ sumsq,
    unsigned long long* hrec,           // [8][2][2048] u64 tagged records (chunk-major)
    unsigned int* ctrl,                 // [0] = rendezvous counter
    float* out)                         // aliases d_out (f32 view) -- no restrict!
{
  __shared__ __align__(16) unsigned char hlds[2][8192];  // [par][4 rows][1024 u] bf16, swizzled
  __shared__ unsigned int lflag[2][32];                  // per-chunk ready flags (=t+1)
  __shared__ unsigned int lcnt[2];                       // per-parity consume counters

  const int tid  = threadIdx.x;
  const int lane = tid & 63;
  const int wid  = tid >> 6;            // [0,4)
  const int lrow = lane & 15, lk = lane >> 4;

  const int g    = blockIdx.x & 7;      // group = 4 batch rows
  const int role = blockIdx.x >> 3;     // [0,32): my chunk / 32-unit block
  const int b0   = g * 4;
  const int u0w  = role * 32 + wid * 8; // this wave's 8 units
  const bool isH = (lrow >= 8);         // B col 0-7 = z, 8-15 = h (packed gates)
  const int unit = u0w + (lrow & 7);
  const int col  = isH ? unit : (1024 + unit);

  // ---- init LDS control state ----
  if (tid < 32) { lflag[0][tid] = 0u; lflag[1][tid] = 0u; }
  if (tid < 2)  { lcnt[tid] = 0u; }

  // ---- BatchNorm scale/bias for this lane's column ----
  float scl, bia;
  {
    float s = sums[col], q = sumsq[col];
    float gam = isH ? gwh[unit] : gwz[unit];
    float bet = isH ? bwh[unit] : bwz[unit];
    float mean = s * (1.0f / 64000.0f);
    float var  = q * (1.0f / 64000.0f) - mean * mean;
    float rstd = rsqrtf(var + BN_EPSF);
    scl = gam * rstd;
    bia = bet - mean * scl;
  }

  // ---- preload this lane's U row (x PKEEP) as 32 MFMA B-fragments (128 VGPRs)
  const float* urow = (isH ? Uh : Uz) + (size_t)unit * 1024;
  bf16x8 bfrag[32];
#pragma unroll
  for (int kt = 0; kt < 32; ++kt) {
    const float4* p4 = (const float4*)(urow + kt * 32 + lk * 8);
    float4 fa = p4[0], fb = p4[1];
    bf16x8 tv;
    tv[0] = (short)f2bf(fa.x * PKEEP); tv[1] = (short)f2bf(fa.y * PKEEP);
    tv[2] = (short)f2bf(fa.z * PKEEP); tv[3] = (short)f2bf(fa.w * PKEEP);
    tv[4] = (short)f2bf(fb.x * PKEEP); tv[5] = (short)f2bf(fb.y * PKEEP);
    tv[6] = (short)f2bf(fb.z * PKEEP); tv[7] = (short)f2bf(fb.w * PKEEP);
    bfrag[kt] = tv;
  }

  // ---- P prefetch prologue: pf=P[0], pn1=P[1] ----
  unsigned short pf[4], pn1[4];
#pragma unroll
  for (int rr = 0; rr < 4; ++rr) {
    pf[rr]  = P[(size_t)(b0 + rr) * NCOLS + col];
    pn1[rr] = P[(size_t)(32 + b0 + rr) * NCOLS + col];
  }
  __syncthreads();   // drains vmcnt + makes LDS init visible

  // ---- rendezvous: ALL WGs' initial P loads drained before anyone writes out[0/1]
  if (tid == 0) {
    __hip_atomic_fetch_add(&ctrl[0], 1u, __ATOMIC_RELEASE, __HIP_MEMORY_SCOPE_SYSTEM);
    while (__hip_atomic_load(&ctrl[0], __ATOMIC_RELAXED, __HIP_MEMORY_SCOPE_SYSTEM) < NWG)
      __builtin_amdgcn_s_sleep(8);
  }
  __syncthreads();

  float hown[4] = {0.f, 0.f, 0.f, 0.f};

  for (int t = 0; t < T_STEPS; ++t) {
    const int par  = t & 1;
    const int npar = (t + 1) & 1;

    // ---- 0. P[t+2] prefetch (drained by staging waitcnt; data used at t+2) ----
    unsigned short pn2[4] = {0, 0, 0, 0};
    if (t + 2 < T_STEPS) {
#pragma unroll
      for (int rr = 0; rr < 4; ++rr)
        pn2[rr] = P[(size_t)((t + 2) * 32 + b0 + rr) * NCOLS + col];
    }

    // ---- 1. issue staging loads: my 8 chunks (c = wid + 4i), 1 record/lane ----
    const unsigned long long* rb = hrec + (((size_t)(g * 2 + par)) << 11);
    unsigned long long rec[8];
#pragma unroll
    for (int i = 0; i < 8; ++i)
      rec[i] = __hip_atomic_load(rb + (wid + i * 4) * 64 + lane,
                                 __ATOMIC_RELAXED, __HIP_MEMORY_SCOPE_SYSTEM);

    // ---- 2. hlds[par] WAR gate: all 4 waves consumed step t-2 (overlaps load lat)
    if (t >= 2) {
      unsigned need = 4u * (unsigned)(t >> 1);
      while (__hip_atomic_load(&lcnt[par], __ATOMIC_ACQUIRE,
                               __HIP_MEMORY_SCOPE_WORKGROUP) < need)
        __builtin_amdgcn_s_sleep(1);
    }

    // ---- 3. validate chunks; write good ones to LDS + release flag; retry stale
    {
      unsigned done = 0;
      while (done != 0xFFu) {
#pragma unroll
        for (int i = 0; i < 8; ++i) {
          if (done & (1u << i)) continue;
          if (__all((int)((unsigned)(rec[i] >> 32) >= (unsigned)t))) {
            int c = wid + i * 4;
            int row = lane >> 4;
            int boff = (row * 2048 + c * 64 + (lane & 15) * 4) ^ ((row & 3) << 5);
            *(unsigned*)(hlds[par] + boff) = (unsigned)rec[i];
            __hip_atomic_store(&lflag[par][c], (unsigned)(t + 1),
                               __ATOMIC_RELEASE, __HIP_MEMORY_SCOPE_WORKGROUP);
            done |= (1u << i);
          } else {
            rec[i] = __hip_atomic_load(rb + (wid + i * 4) * 64 + lane,
                                       __ATOMIC_RELAXED, __HIP_MEMORY_SCOPE_SYSTEM);
          }
        }
        if (done != 0xFFu) __builtin_amdgcn_s_sleep(1);
      }
    }

    // ---- 4. consume 32 chunks: acquire-spin LDS flag -> ds_read -> MFMA ----
    f32x4 ac0 = {0.f, 0.f, 0.f, 0.f}, ac1 = ac0, ac2 = ac0, ac3 = ac0;
#pragma unroll
    for (int c = 0; c < 32; ++c) {
      while (__hip_atomic_load(&lflag[par][c], __ATOMIC_ACQUIRE,
                               __HIP_MEMORY_SCOPE_WORKGROUP) < (unsigned)(t + 1)) { }
      int ab = ((lane & 3) * 2048 + c * 64 + lk * 16) ^ ((lane & 3) << 5);
      bf16x8 af = *(const bf16x8*)(hlds[par] + ab);
      if ((c & 3) == 0)      ac0 = __builtin_amdgcn_mfma_f32_16x16x32_bf16(af, bfrag[c], ac0, 0, 0, 0);
      else if ((c & 3) == 1) ac1 = __builtin_amdgcn_mfma_f32_16x16x32_bf16(af, bfrag[c], ac1, 0, 0, 0);
      else if ((c & 3) == 2) ac2 = __builtin_amdgcn_mfma_f32_16x16x32_bf16(af, bfrag[c], ac2, 0, 0, 0);
      else                   ac3 = __builtin_amdgcn_mfma_f32_16x16x32_bf16(af, bfrag[c], ac3, 0, 0, 0);
    }
    // release my consumption of hlds[par] (unblocks staging of step t+2)
    if (lane == 0)
      __hip_atomic_fetch_add(&lcnt[par], 1u, __ATOMIC_RELEASE, __HIP_MEMORY_SCOPE_WORKGROUP);

    f32x4 dsum = (ac0 + ac1) + (ac2 + ac3);

    // ---- 5. epilogue: z meets h via shfl_xor(8); lanes 8-15 own the update ----
    float pre[4], oth[4];
#pragma unroll
    for (int rr = 0; rr < 4; ++rr) {
      pre[rr] = dsum[rr] + bf2f(pf[rr]) * scl + bia;
      oth[rr] = __shfl_xor(pre[rr], 8);     // all lanes participate
    }

    if (lk == 0 && isH) {                    // lanes 8..15: pre=h-pre, oth=z-pre
      float hn[4];
#pragma unroll
      for (int rr = 0; rr < 4; ++rr) {
        float zz = 1.0f / (1.0f + __expf(-oth[rr]));
        float hc = fmaxf(pre[rr], 0.0f) * PKEEP;      // relu * 'orig' dropout
        hn[rr] = zz * hown[rr] + (1.0f - zz) * hc;
        hown[rr] = hn[rr];
      }
      float pp[4];
#pragma unroll
      for (int rr = 0; rr < 4; ++rr) pp[rr] = __shfl_xor(hn[rr], 1);  // 8<->9 etc
      if ((lane & 1) == 0) {                 // lanes 8,10,12,14: even units
        // WAR belt-and-braces: all prior P loads drained (already true via staging)
        asm volatile("s_waitcnt vmcnt(0)" ::: "memory");
        int pairIdx = wid * 4 + ((lane - 8) >> 1);
        unsigned long long* hbn = hrec + (((size_t)(g * 2 + npar)) << 11)
                                + role * 64 + pairIdx;
        unsigned tagw = (unsigned)(t + 1);
#pragma unroll
        for (int rr = 0; rr < 4; ++rr) {
          unsigned long long rcd = ((unsigned long long)tagw << 32)
                                 | (unsigned)f2bf(hn[rr]) | ((unsigned)f2bf(pp[rr]) << 16);
          __hip_atomic_store(hbn + rr * 16, rcd,
                             __ATOMIC_RELAXED, __HIP_MEMORY_SCOPE_SYSTEM);
        }
#pragma unroll
        for (int rr = 0; rr < 4; ++rr) {
          float2 ov = {hn[rr], pp[rr]};
          *(float2*)(out + (size_t)(t * 32 + b0 + rr) * 1024 + unit) = ov;
        }
      }
    }

#pragma unroll
    for (int rr = 0; rr < 4; ++rr) { pf[rr] = pn1[rr]; pn1[rr] = pn2[rr]; }
  }
}

// ---------------- launch ----------------
extern "C" void kernel_launch(void* const* d_in, const int* in_sizes, int n_in,
                              void* d_out, int out_size, void* d_ws, size_t ws_size,
                              hipStream_t stream) {
  (void)in_sizes; (void)n_in; (void)out_size; (void)ws_size;
  const float* x   = (const float*)d_in[0];
  const float* Wh  = (const float*)d_in[1];
  const float* Wz  = (const float*)d_in[2];
  const float* Uh  = (const float*)d_in[3];
  const float* Uz  = (const float*)d_in[4];
  const float* gwh = (const float*)d_in[5];
  const float* bwh = (const float*)d_in[6];
  const float* gwz = (const float*)d_in[7];
  const float* bwz = (const float*)d_in[8];

  char* ws = (char*)d_ws;
  float*              sums  = (float*)(ws + 0);                  // 8192 B
  float*              sumsq = (float*)(ws + 8192);               // 8192 B
  unsigned long long* hrec  = (unsigned long long*)(ws + 16384); // 262144 B
  unsigned int*       ctrl  = (unsigned int*)(ws + 278528);      // 128 B
  unsigned short*     Wb    = (unsigned short*)(ws + 278784);    // 2 MiB

  // zero stats + records + ctrl every call (graph-replay safe; tag=0 == valid h0=0)
  hipMemsetAsync(d_ws, 0, 278784, stream);
  k_convw<<<1024, 256, 0, stream>>>(Wh, Wz, Wb);
  // P (bf16) lives in d_out; scan overwrites it with f32 output in provably-ordered fashion
  k_gemm<<<8000, 256, 0, stream>>>(x, Wb, (unsigned short*)d_out, sums, sumsq);
  k_scan<<<NWG, 256, 0, stream>>>(Uh, Uz, gwh, bwh, gwz, bwz,
                                  (const unsigned short*)d_out, sums, sumsq,
                                  hrec, ctrl, (float*)d_out);
}

// Round 9
// 7684.557 us; speedup vs baseline: 1.8077x; 1.8077x over previous
//
#include <hip/hip_runtime.h>

// liGRU on MI355X.
// Phase 1: P[64000][2048](bf16, in d_out) = x @ [Wh;Wz]^T + column sums/sumsq.
// Phase 2: persistent scan, 8 groups (4 batch rows) x 32 WGs, 4 waves/WG.
//          Each wave owns 8 units and computes BOTH gates via packed MFMA B:
//          B cols 0-7 = Uz rows, cols 8-15 = Uh rows of the same units
//          (bfrag[32] = 128 VGPRs -- no spills). z meets h via __shfl_xor(pre,8):
//          no zlds, one raw s_barrier per step.
//          Exchange protocol: u64 records { tag=t+1 (hi32) | 2x bf16 h (lo32) }
//          -- flag IS the data, per-record tag verified on read with retry.
//          ROUND 9 CHANGE (single variable vs r5): all exchange atomics are
//          __HIP_MEMORY_SCOPE_AGENT (device scope, LLC coherence point) instead
//          of SYSTEM (host-coherent, suspected HBM-path). Agent scope is
//          cross-XCD coherent by definition (atomicAdd default, m20-verified).
//          Lessons kept: no sc0/sc1 hand asm (r4 hang), no tag indirection
//          (r6 regression), no >128-VGPR fragments (r3 spill), no LDS
//          handshakes inside the K-loop (r8 regression).
//          WAR on d_out aliasing (P bf16 read vs out f32 write): P[t+1]
//          prefetches (issued step t-1) are drained by step t's vmcnt(0) BEFORE
//          any tag-(t+1) record store; a writer of out[t+1] passed poll(t+1),
//          i.e. saw all tags>=t+1, hence all P[t+1] reads completed. Prologue
//          rendezvous covers P[0..1].

#define T_STEPS 2000
#define NCOLS   2048
#define PKEEP   0.8f
#define BN_EPSF 1e-5f
#define NW      256

typedef __attribute__((ext_vector_type(8))) short bf16x8;
typedef __attribute__((ext_vector_type(4))) float f32x4;
typedef __attribute__((ext_vector_type(4))) unsigned int u32x4;

static __device__ __forceinline__ unsigned short f2bf(float f) {
  unsigned u = __builtin_bit_cast(unsigned, f);
  unsigned r = u + 0x7FFFu + ((u >> 16) & 1u);   // RNE
  return (unsigned short)(r >> 16);
}
static __device__ __forceinline__ float bf2f(unsigned short s) {
  unsigned u = ((unsigned)s) << 16;
  return __builtin_bit_cast(float, u);
}

// ---------------- K1: convert [Wh;Wz] f32 -> bf16 ----------------
__global__ void k_convw(const float* __restrict__ Wh, const float* __restrict__ Wz,
                        unsigned short* __restrict__ Wb) {
  int i = blockIdx.x * 256 + threadIdx.x;
  int e = i * 4;
  int n = e >> 9;
  int k = e & 511;
  const float* src = (n < 1024) ? (Wh + (size_t)n * 512 + k)
                                : (Wz + (size_t)(n - 1024) * 512 + k);
  float4 v = *(const float4*)src;
  *(ushort4*)(Wb + e) = make_ushort4(f2bf(v.x), f2bf(v.y), f2bf(v.z), f2bf(v.w));
}

// ---------------- K2: GEMM  P = x @ Wb^T  (+ BN stats) ----------------
__global__ __launch_bounds__(256, 2) void k_gemm(
    const float* __restrict__ X, const unsigned short* __restrict__ Wb,
    unsigned short* __restrict__ P, float* __restrict__ sums, float* __restrict__ sumsq) {
  __shared__ __align__(16) unsigned short As[128 * 32];
  __shared__ __align__(16) unsigned short Bs[128 * 32];
  const int tid  = threadIdx.x;
  const int bm   = blockIdx.x >> 4, bn = blockIdx.x & 15;
  const int lane = tid & 63, wid = tid >> 6;
  const int wm   = wid >> 1, wn = wid & 1;
  const int lrow = lane & 15, lk = lane >> 4;

  f32x4 acc[4][4] = {};

  for (int kk = 0; kk < 512; kk += 32) {
    __syncthreads();
#pragma unroll
    for (int j = 0; j < 2; ++j) {
      int c = j * 256 + wid * 64 + lane;
      int brow = c >> 2, b8 = (c & 3) * 8;
      const unsigned short* gp = Wb + (size_t)(bn * 128 + brow) * 512 + kk + b8;
      __builtin_amdgcn_global_load_lds(
          (const __attribute__((address_space(1))) unsigned int*)gp,
          (__attribute__((address_space(3))) unsigned int*)(Bs + (size_t)(j * 256 + wid * 64) * 8),
          16, 0, 0);
    }
    {
      int arow = tid >> 1, ahalf = tid & 1;
      const float4* xp = (const float4*)(X + (size_t)(bm * 128 + arow) * 512 + kk + ahalf * 16);
      unsigned v[8];
#pragma unroll
      for (int j = 0; j < 4; ++j) {
        float4 f = xp[j];
        v[j * 2 + 0] = (unsigned)f2bf(f.x) | ((unsigned)f2bf(f.y) << 16);
        v[j * 2 + 1] = (unsigned)f2bf(f.z) | ((unsigned)f2bf(f.w) << 16);
      }
      u32x4* ap = (u32x4*)(As + arow * 32 + ahalf * 16);
      u32x4 t0 = {v[0], v[1], v[2], v[3]};
      u32x4 t1 = {v[4], v[5], v[6], v[7]};
      ap[0] = t0; ap[1] = t1;
    }
    __syncthreads();

    bf16x8 af[4], bfr[4];
#pragma unroll
    for (int mt = 0; mt < 4; ++mt)
      af[mt] = *(const bf16x8*)(As + (wm * 64 + mt * 16 + lrow) * 32 + lk * 8);
#pragma unroll
    for (int nt = 0; nt < 4; ++nt)
      bfr[nt] = *(const bf16x8*)(Bs + (wn * 64 + nt * 16 + lrow) * 32 + lk * 8);
#pragma unroll
    for (int mt = 0; mt < 4; ++mt)
#pragma unroll
      for (int nt = 0; nt < 4; ++nt)
        acc[mt][nt] = __builtin_amdgcn_mfma_f32_16x16x32_bf16(af[mt], bfr[nt], acc[mt][nt], 0, 0, 0);
  }

#pragma unroll
  for (int mt = 0; mt < 4; ++mt)
#pragma unroll
    for (int nt = 0; nt < 4; ++nt) {
      f32x4 a = acc[mt][nt];
      int gcol  = bn * 128 + wn * 64 + nt * 16 + lrow;
      int grow0 = bm * 128 + wm * 64 + mt * 16 + lk * 4;
#pragma unroll
      for (int rr = 0; rr < 4; ++rr)
        P[(size_t)(grow0 + rr) * NCOLS + gcol] = f2bf(a[rr]);
    }
#pragma unroll
  for (int nt = 0; nt < 4; ++nt) {
    float s = 0.f, q = 0.f;
#pragma unroll
    for (int mt = 0; mt < 4; ++mt) {
      f32x4 a = acc[mt][nt];
#pragma unroll
      for (int rr = 0; rr < 4; ++rr) { s += a[rr]; q += a[rr] * a[rr]; }
    }
    s += __shfl_xor(s, 16); s += __shfl_xor(s, 32);
    q += __shfl_xor(q, 16); q += __shfl_xor(q, 32);
    if (lane < 16) {
      int gcol = bn * 128 + wn * 64 + nt * 16 + lrow;
      atomicAdd(&sums[gcol], s);
      atomicAdd(&sumsq[gcol], q);
    }
  }
}

// ---------------- K3: persistent scan ----------------
__global__ __launch_bounds__(256, 1) void k_scan(
    const float* __restrict__ Uh, const float* __restrict__ Uz,
    const float* __restrict__ gwh, const float* __restrict__ bwh,
    const float* __restrict__ gwz, const float* __restrict__ bwz,
    const unsigned short* P,            // aliases d_out (bf16 view) -- no restrict!
    const float* __restrict__ sums, const float* __restrict__ sumsq,
    unsigned long long* hrec,           // [8][2][2048] u64 records
    unsigned int* ctrl,                 // [0]=rendezvous counter
    float* out)                         // aliases d_out (f32 view) -- no restrict!
{
  // hlds double-buffered by step parity: [2][4 rows][1024 units] bf16, XOR-swizzled
  __shared__ __align__(16) unsigned char hlds[16384];

  const int tid  = threadIdx.x;
  const int lane = tid & 63;
  const int wid  = tid >> 6;
  const int lrow = lane & 15, lk = lane >> 4;

  const int g    = blockIdx.x & 7;       // group = 4 batch rows
  const int role = blockIdx.x >> 3;      // [0,32): unit block
  const int b0   = g * 4;
  const int u0w  = role * 32 + wid * 8;  // this wave's 8 units
  const bool isH = (lrow >= 8);          // B col 0-7 = z, 8-15 = h
  const int unit = u0w + (lrow & 7);
  const int col  = isH ? unit : (1024 + unit);   // P column for this lane's gate

  // ---- BatchNorm scale/bias for this lane's column ----
  float scl, bia;
  {
    float s = sums[col], q = sumsq[col];
    float gam = isH ? gwh[unit] : gwz[unit];
    float bet = isH ? bwh[unit] : bwz[unit];
    float mean = s * (1.0f / 64000.0f);
    float var  = q * (1.0f / 64000.0f) - mean * mean;
    float rstd = rsqrtf(var + BN_EPSF);
    scl = gam * rstd;
    bia = bet - mean * scl;
  }

  // ---- preload this lane's U row (x PKEEP) as 32 MFMA B-fragments (128 VGPRs)
  //      packed: B rows 0-7 = Uz[u0w..], rows 8-15 = Uh[u0w..]
  const float* urow = (isH ? Uh : Uz) + (size_t)unit * 1024;
  bf16x8 bfrag[32];
#pragma unroll
  for (int kt = 0; kt < 32; ++kt) {
    const float4* p4 = (const float4*)(urow + kt * 32 + lk * 8);
    float4 fa = p4[0], fb = p4[1];
    bf16x8 tv;
    tv[0] = (short)f2bf(fa.x * PKEEP); tv[1] = (short)f2bf(fa.y * PKEEP);
    tv[2] = (short)f2bf(fa.z * PKEEP); tv[3] = (short)f2bf(fa.w * PKEEP);
    tv[4] = (short)f2bf(fb.x * PKEEP); tv[5] = (short)f2bf(fb.y * PKEEP);
    tv[6] = (short)f2bf(fb.z * PKEEP); tv[7] = (short)f2bf(fb.w * PKEEP);
    bfrag[kt] = tv;
  }

  // ---- P prefetch prologue: pf=P[0], pn1=P[1] ----
  unsigned short pf[4], pn1[4];
#pragma unroll
  for (int rr = 0; rr < 4; ++rr) {
    pf[rr]  = P[(size_t)(b0 + rr) * NCOLS + col];
    pn1[rr] = P[(size_t)(32 + b0 + rr) * NCOLS + col];
  }
  __syncthreads();   // full drain: my initial P loads complete

  // ---- rendezvous: ALL WGs' initial P loads drained before anyone can write
  //      out rows 0/1 (WAR on the d_out aliasing).
  if (tid == 0) {
    __hip_atomic_fetch_add(&ctrl[0], 1u, __ATOMIC_RELEASE, __HIP_MEMORY_SCOPE_AGENT);
    while (__hip_atomic_load(&ctrl[0], __ATOMIC_RELAXED, __HIP_MEMORY_SCOPE_AGENT) < NW)
      __builtin_amdgcn_s_sleep(8);
  }
  __syncthreads();

  float hown[4] = {0.f, 0.f, 0.f, 0.f};

  for (int t = 0; t < T_STEPS; ++t) {
    const int par = t & 1;

    // ---- 1. poll this thread's 8 records (parity par); tag carries the data.
    //      AGENT scope: device-coherent at the LLC (vs SYSTEM's host-coherent path).
    const unsigned long long* rb = hrec + (((size_t)(g * 2 + par)) << 11) + tid;
    unsigned long long rec[8];
#pragma unroll
    for (int j = 0; j < 8; ++j)
      rec[j] = __hip_atomic_load(rb + 256 * j, __ATOMIC_RELAXED, __HIP_MEMORY_SCOPE_AGENT);
    while (true) {
      unsigned bad = 0;
#pragma unroll
      for (int j = 0; j < 8; ++j)
        if ((unsigned)(rec[j] >> 32) < (unsigned)t) bad |= (1u << j);
      if (!bad) break;
      __builtin_amdgcn_s_sleep(1);
#pragma unroll
      for (int j = 0; j < 8; ++j)
        if (bad & (1u << j))
          rec[j] = __hip_atomic_load(rb + 256 * j, __ATOMIC_RELAXED, __HIP_MEMORY_SCOPE_AGENT);
    }
    // full vmem drain: P[t+1] (issued last step) completed -> WAR proof for tag t+1
    asm volatile("s_waitcnt vmcnt(0)" ::: "memory");

    // ---- 2. prefetch P[t+2]: rides across barrier + all stores until next poll
    unsigned short pn2[4] = {0, 0, 0, 0};
    if (t + 2 < T_STEPS) {
#pragma unroll
      for (int rr = 0; rr < 4; ++rr)
        pn2[rr] = P[(size_t)((t + 2) * 32 + b0 + rr) * NCOLS + col];
    }

    // ---- 3. unpack h records into hlds[par] (XOR-swizzled) ----
    unsigned char* hb = hlds + par * 8192;
#pragma unroll
    for (int j = 0; j < 8; ++j) {
      int idx = tid + 256 * j;
      int row = idx >> 9, up = idx & 511;
      int byteoff = (row * 2048 + up * 4) ^ ((row & 3) << 5);
      *(unsigned*)(hb + byteoff) = (unsigned)rec[j];
    }
    // single raw barrier per step: LDS-only drain; P[t+2] stays in flight
    asm volatile("s_waitcnt lgkmcnt(0)" ::: "memory");
    __builtin_amdgcn_sched_barrier(0);
    __builtin_amdgcn_s_barrier();
    __builtin_amdgcn_sched_barrier(0);

    // ---- 4. packed dot: one MFMA stream computes BOTH gates ----
    f32x4 ac0 = {0.f, 0.f, 0.f, 0.f}, ac1 = ac0, ac2 = ac0, ac3 = ac0;
#pragma unroll
    for (int kt = 0; kt < 32; ++kt) {
      int ab = ((lane & 3) * 2048 + kt * 64 + lk * 16) ^ ((lane & 3) << 5);
      bf16x8 af = *(const bf16x8*)(hb + ab);
      if ((kt & 3) == 0)      ac0 = __builtin_amdgcn_mfma_f32_16x16x32_bf16(af, bfrag[kt], ac0, 0, 0, 0);
      else if ((kt & 3) == 1) ac1 = __builtin_amdgcn_mfma_f32_16x16x32_bf16(af, bfrag[kt], ac1, 0, 0, 0);
      else if ((kt & 3) == 2) ac2 = __builtin_amdgcn_mfma_f32_16x16x32_bf16(af, bfrag[kt], ac2, 0, 0, 0);
      else                    ac3 = __builtin_amdgcn_mfma_f32_16x16x32_bf16(af, bfrag[kt], ac3, 0, 0, 0);
    }
    f32x4 dsum = (ac0 + ac1) + (ac2 + ac3);

    // ---- 5. epilogue: z meets h via shfl_xor(8); lanes 8-15 own the update ----
    float pre[4], oth[4];
#pragma unroll
    for (int rr = 0; rr < 4; ++rr) {
      pre[rr] = dsum[rr] + bf2f(pf[rr]) * scl + bia;
      oth[rr] = __shfl_xor(pre[rr], 8);     // all lanes participate
    }

    if (lk == 0 && isH) {                    // lanes 8..15: pre=h-pre, oth=z-pre
      float hn[4];
#pragma unroll
      for (int rr = 0; rr < 4; ++rr) {
        float zz = 1.0f / (1.0f + __expf(-oth[rr]));
        float hc = fmaxf(pre[rr], 0.0f) * PKEEP;      // relu * 'orig' dropout
        hn[rr] = zz * hown[rr] + (1.0f - zz) * hc;
        hown[rr] = hn[rr];
      }
      float pp[4];
#pragma unroll
      for (int rr = 0; rr < 4; ++rr) pp[rr] = __shfl_xor(hn[rr], 1);  // 8<->9 etc
      if ((lane & 1) == 0) {                 // lanes 8,10,12,14: even units
        unsigned long long* hbn = hrec + (((size_t)(g * 2 + ((t + 1) & 1))) << 11)
                                + (unit >> 1);
        unsigned tagw = (unsigned)(t + 1);
#pragma unroll
        for (int rr = 0; rr < 4; ++rr) {
          unsigned long long rcd = ((unsigned long long)tagw << 32)
                                 | (unsigned)f2bf(hn[rr]) | ((unsigned)f2bf(pp[rr]) << 16);
          __hip_atomic_store(hbn + rr * 512, rcd,
                             __ATOMIC_RELAXED, __HIP_MEMORY_SCOPE_AGENT);
        }
#pragma unroll
        for (int rr = 0; rr < 4; ++rr) {
          float2 ov = {hn[rr], pp[rr]};
          *(float2*)(out + (size_t)(t * 32 + b0 + rr) * 1024 + unit) = ov;
        }
      }
    }

#pragma unroll
    for (int rr = 0; rr < 4; ++rr) { pf[rr] = pn1[rr]; pn1[rr] = pn2[rr]; }
  }
}

// ---------------- launch ----------------
extern "C" void kernel_launch(void* const* d_in, const int* in_sizes, int n_in,
                              void* d_out, int out_size, void* d_ws, size_t ws_size,
                              hipStream_t stream) {
  (void)in_sizes; (void)n_in; (void)out_size; (void)ws_size;
  const float* x   = (const float*)d_in[0];
  const float* Wh  = (const float*)d_in[1];
  const float* Wz  = (const float*)d_in[2];
  const float* Uh  = (const float*)d_in[3];
  const float* Uz  = (const float*)d_in[4];
  const float* gwh = (const float*)d_in[5];
  const float* bwh = (const float*)d_in[6];
  const float* gwz = (const float*)d_in[7];
  const float* bwz = (const float*)d_in[8];

  char* ws = (char*)d_ws;
  float*              sums  = (float*)(ws + 0);                  // 8192 B
  float*              sumsq = (float*)(ws + 8192);               // 8192 B
  unsigned long long* hrec  = (unsigned long long*)(ws + 16384); // 262144 B
  unsigned int*       ctrl  = (unsigned int*)(ws + 278528);      // 128 B
  unsigned short*     Wb    = (unsigned short*)(ws + 278784);    // 2 MiB

  // zero stats + records + ctrl every call (graph-replay safe; tag=0 == valid h0=0)
  hipMemsetAsync(d_ws, 0, 278784, stream);
  k_convw<<<1024, 256, 0, stream>>>(Wh, Wz, Wb);
  // P (bf16) lives in d_out; scan overwrites it with f32 output in provably-ordered fashion
  k_gemm<<<8000, 256, 0, stream>>>(x, Wb, (unsigned short*)d_out, sums, sumsq);
  k_scan<<<NW, 256, 0, stream>>>(Uh, Uz, gwh, bwh, gwz, bwz,
                                 (const unsigned short*)d_out, sums, sumsq,
                                 hrec, ctrl, (float*)d_out);
}